// Round 16
// baseline (205.779 us; speedup 1.0000x reference)
//
#include <hip/hip_runtime.h>
#include <hip/hip_bf16.h>

// Performer (FAVOR+) causal linear self-attention, MI355X round 15.
// B=4 L=4096 E=512 H=8 D=64 M=256 chunk=128.
// Round 15: k_kmaxM folded into k_qkv via PW = DN*proj@Wk (xd(k) = bf16(x)@PW^T
// computed from the fk frags qkv already holds; global-max shift cancels in
// num/den); prefix loops unrolled x4 to pipeline the serial plane chain.
// cattn12/chunkKV6/proj_M2 byte-identical to round 14.

#define BB 4
#define LL 4096
#define EE 512
#define HH 8
#define DD 64
#define MM 256
#define CC 128
#define NCH 32   // L / CC
#define BHN 32   // B * H

constexpr float DN    = 0.35355339059327373f; // 64^-0.25
constexpr float DIAGC = 0.0625f;              // 0.5 * dn^2
constexpr float RATIO = 0.0625f;              // 256^-0.5
constexpr float EPSV  = 1e-4f;
constexpr float L2E   = 1.4426950408889634f;  // log2(e)
constexpr float CEPS  = 6.25e-6f;             // RATIO*EPSV

typedef __attribute__((ext_vector_type(8))) short bf16x8;
typedef __attribute__((ext_vector_type(4))) float f32x4;
union FU { uint4 u; bf16x8 b; };
__device__ __forceinline__ bf16x8 asb(uint4 u){ FU f; f.u = u; return f.b; }
union PK8 { unsigned short s[8]; uint4 u; };
union PK4 { unsigned short s[4]; uint2 u; };

__device__ __forceinline__ unsigned short f2bf(float f){
  unsigned u = __float_as_uint(f);
  u = u + 0x7FFFu + ((u >> 16) & 1u);   // RTNE
  return (unsigned short)(u >> 16);
}
__device__ __forceinline__ float bfl(unsigned u){ return __uint_as_float(u << 16); }
__device__ __forceinline__ unsigned bfpair(float lo, float hi){
  return (unsigned)f2bf(lo) | ((unsigned)f2bf(hi) << 16);
}
// RATIO*(exp(x - bs) + EPSV) == exp2(x*L2E + nb) + CEPS with nb = -(bs*L2E + 4)
__device__ __forceinline__ float pexp(float x, float nb){
  return exp2f(fmaf(x, L2E, nb)) + CEPS;
}
__device__ __forceinline__ unsigned enc_f32(float f){
  unsigned u = __float_as_uint(f);
  return (u & 0x80000000u) ? ~u : (u | 0x80000000u);
}
__device__ __forceinline__ float dec_f32(unsigned u){
  unsigned v = (u & 0x80000000u) ? (u & 0x7FFFFFFFu) : ~u;
  return __uint_as_float(v);
}
__device__ __forceinline__ uint4 pack8(float4 a, float4 b){
  PK8 p;
  p.s[0] = f2bf(a.x); p.s[1] = f2bf(a.y); p.s[2] = f2bf(a.z); p.s[3] = f2bf(a.w);
  p.s[4] = f2bf(b.x); p.s[5] = f2bf(b.y); p.s[6] = f2bf(b.z); p.s[7] = f2bf(b.w);
  return p.u;
}

// ---------------- K0: Wout/proj f32 -> bf16, plus PW = DN*proj@Wk -> bf16 ----------------
__global__ __launch_bounds__(256) void k_cvt(const float* __restrict__ Wout,
                                             unsigned short* __restrict__ Woutb,
                                             const float* __restrict__ proj,
                                             unsigned short* __restrict__ projb,
                                             const float* __restrict__ Wk,
                                             unsigned short* __restrict__ PWb){
  int bid = blockIdx.x, tid = threadIdx.x;
  if (bid < 512){
    int idx = bid * 256 + tid;
    float2 v = reinterpret_cast<const float2*>(Wout)[idx];
    reinterpret_cast<unsigned*>(Woutb)[idx] = bfpair(v.x, v.y);
  } else if (bid < 544){
    int idx = (bid - 512) * 256 + tid;
    float2 v = reinterpret_cast<const float2*>(proj)[idx];
    reinterpret_cast<unsigned*>(projb)[idx] = bfpair(v.x * DN, v.y * DN);
  } else {
    // PW[m][dp] = DN * sum_d proj[m][d] * Wk[d][dp]  (f32, then bf16)
    int idx = (bid - 544) * 256 + tid;   // 64 blocks -> 16384 elements
    int m = idx >> 6, dp = idx & 63;
    float s = 0.f;
    #pragma unroll 8
    for (int d = 0; d < 64; ++d)
      s += proj[m * 64 + d] * Wk[d * 64 + dp];
    PWb[idx] = f2bf(DN * s);
  }
}

// ---------------- K1: fused MFMA qkv transform + global k-max ----------------
__global__ __launch_bounds__(256) void k_qkv(const float* __restrict__ xq,
                                             const float* __restrict__ xk,
                                             const float* __restrict__ xv,
                                             const float* __restrict__ Wq,
                                             const float* __restrict__ Wk,
                                             const float* __restrict__ Wv,
                                             const unsigned short* __restrict__ PWb,
                                             unsigned short* __restrict__ qhb,
                                             unsigned short* __restrict__ khb,
                                             unsigned short* __restrict__ vTb,
                                             float* __restrict__ rsq,
                                             float* __restrict__ rsk,
                                             unsigned* __restrict__ kmaxp){
  __shared__ unsigned short Wl[3 * 64 * 64];   // 24KB swizzled bf16
  __shared__ float red[4];
  int tid = threadIdx.x;
  for (int idx = tid; idx < 3 * 64 * 8; idx += 256){
    int sel = idx >> 9, rem = idx & 511, row = rem >> 3, ch = rem & 7;
    const float* Wp = sel == 0 ? Wq : (sel == 1 ? Wk : Wv);
    const float4* w4 = reinterpret_cast<const float4*>(Wp) + row * 16 + ch * 2;
    int byte = sel * 8192 + row * 128 + ((ch * 16) ^ ((row & 7) << 4));
    *reinterpret_cast<uint4*>(reinterpret_cast<char*>(Wl) + byte) = pack8(w4[0], w4[1]);
  }
  __syncthreads();
  int w = tid >> 6, lane = tid & 63, l15 = lane & 15, g = lane >> 4;
  int bh = blockIdx.x >> 5, lb = blockIdx.x & 31;
  int b = bh >> 3, h = bh & 7;
  const char* Wc = reinterpret_cast<const char*>(Wl);
  const uint4* pw4 = reinterpret_cast<const uint4*>(PWb);
  float mxk = -3.0e38f;
  #pragma unroll
  for (int tt = 0; tt < 2; ++tt){
    int lt = w * 2 + tt;
    int l = lb * 128 + lt * 16 + l15;
    size_t xoff = ((size_t)(b * LL + l)) * EE + h * DD;
    const float4* q4 = reinterpret_cast<const float4*>(xq + xoff);
    const float4* k4 = reinterpret_cast<const float4*>(xk + xoff);
    const float4* v4 = reinterpret_cast<const float4*>(xv + xoff);
    uint4 fq[2], fk[2], fv[2];
    #pragma unroll
    for (int ks = 0; ks < 2; ++ks){
      int fi = ks * 8 + g * 2;
      fq[ks] = pack8(q4[fi], q4[fi + 1]);
      fk[ks] = pack8(k4[fi], k4[fi + 1]);
      fv[ks] = pack8(v4[fi], v4[fi + 1]);
    }
    size_t grow = (size_t)bh * LL + l;
    // ---- q ----
    {
      float ss = 0.f;
      #pragma unroll
      for (int dt = 0; dt < 4; ++dt){
        int row = dt * 16 + l15;
        f32x4 acc = {0.f, 0.f, 0.f, 0.f};
        #pragma unroll
        for (int ks = 0; ks < 2; ++ks){
          int byte = 0 * 8192 + row * 128 + ((ks * 64 + g * 16) ^ ((row & 7) << 4));
          uint4 wf = *reinterpret_cast<const uint4*>(Wc + byte);
          acc = __builtin_amdgcn_mfma_f32_16x16x32_bf16(asb(wf), asb(fq[ks]), acc, 0, 0, 0);
        }
        ss += acc[0]*acc[0] + acc[1]*acc[1] + acc[2]*acc[2] + acc[3]*acc[3];
        ushort4 pk;
        pk.x = f2bf(acc[0]); pk.y = f2bf(acc[1]); pk.z = f2bf(acc[2]); pk.w = f2bf(acc[3]);
        *reinterpret_cast<ushort4*>(qhb + grow * 64 + dt * 16 + g * 4) = pk;
      }
      ss += __shfl_xor(ss, 16, 64);
      ss += __shfl_xor(ss, 32, 64);
      if (g == 0) rsq[grow] = ss;
    }
    // ---- k ----
    {
      float ss = 0.f;
      #pragma unroll
      for (int dt = 0; dt < 4; ++dt){
        int row = dt * 16 + l15;
        f32x4 acc = {0.f, 0.f, 0.f, 0.f};
        #pragma unroll
        for (int ks = 0; ks < 2; ++ks){
          int byte = 1 * 8192 + row * 128 + ((ks * 64 + g * 16) ^ ((row & 7) << 4));
          uint4 wf = *reinterpret_cast<const uint4*>(Wc + byte);
          acc = __builtin_amdgcn_mfma_f32_16x16x32_bf16(asb(wf), asb(fk[ks]), acc, 0, 0, 0);
        }
        ss += acc[0]*acc[0] + acc[1]*acc[1] + acc[2]*acc[2] + acc[3]*acc[3];
        ushort4 pk;
        pk.x = f2bf(acc[0]); pk.y = f2bf(acc[1]); pk.z = f2bf(acc[2]); pk.w = f2bf(acc[3]);
        *reinterpret_cast<ushort4*>(khb + grow * 64 + dt * 16 + g * 4) = pk;
      }
      ss += __shfl_xor(ss, 16, 64);
      ss += __shfl_xor(ss, 32, 64);
      if (g == 0) rsk[grow] = ss;
    }
    // ---- xd(k) global max via PW (uses fk frags; 2 MFMA per m-tile) ----
    #pragma unroll
    for (int mt = 0; mt < 16; ++mt){
      uint4 a0 = pw4[(size_t)(mt * 16 + l15) * 8 + g];
      uint4 a1 = pw4[(size_t)(mt * 16 + l15) * 8 + 4 + g];
      f32x4 acc = {0.f, 0.f, 0.f, 0.f};
      acc = __builtin_amdgcn_mfma_f32_16x16x32_bf16(asb(a0), asb(fk[0]), acc, 0, 0, 0);
      acc = __builtin_amdgcn_mfma_f32_16x16x32_bf16(asb(a1), asb(fk[1]), acc, 0, 0, 0);
      mxk = fmaxf(mxk, fmaxf(fmaxf(acc[0], acc[1]), fmaxf(acc[2], acc[3])));
    }
    // ---- v transposed ----
    #pragma unroll
    for (int dt = 0; dt < 4; ++dt){
      int row = dt * 16 + l15;
      f32x4 acc = {0.f, 0.f, 0.f, 0.f};
      #pragma unroll
      for (int ks = 0; ks < 2; ++ks){
        int byte = 2 * 8192 + row * 128 + ((ks * 64 + g * 16) ^ ((row & 7) << 4));
        uint4 wf = *reinterpret_cast<const uint4*>(Wc + byte);
        acc = __builtin_amdgcn_mfma_f32_16x16x32_bf16(asb(fv[ks]), asb(wf), acc, 0, 0, 0);
      }
      ushort4 pk;
      pk.x = f2bf(acc[0]); pk.y = f2bf(acc[1]); pk.z = f2bf(acc[2]); pk.w = f2bf(acc[3]);
      *reinterpret_cast<ushort4*>(vTb + ((size_t)(bh * DD + dt * 16 + l15)) * LL
                                  + lb * 128 + lt * 16 + g * 4) = pk;
    }
  }
  // block-level max reduce -> 1 atomic per block (1024 total, spread in time)
  #pragma unroll
  for (int off = 32; off >= 1; off >>= 1)
    mxk = fmaxf(mxk, __shfl_xor(mxk, off, 64));
  if (lane == 0) red[w] = mxk;
  __syncthreads();
  if (tid == 0){
    float m = fmaxf(fmaxf(red[0], red[1]), fmaxf(red[2], red[3]));
    atomicMax(kmaxp, enc_f32(m));
  }
}

// ---------------- K3: per-chunk KV sums, mt-outer phi(k) (load-reuse) ----------------
__global__ __launch_bounds__(256, 2) void k_chunkKV6(const unsigned short* __restrict__ khb,
                                                     const unsigned short* __restrict__ projb,
                                                     const float* __restrict__ rsk,
                                                     const unsigned* __restrict__ kmaxp,
                                                     const unsigned short* __restrict__ vTb,
                                                     unsigned short* __restrict__ SpT,
                                                     float* __restrict__ zf){
  __shared__ unsigned kL[4 * 128 * 33];    // 67.6 KiB, per-wave panels
  int tid = threadIdx.x;
  int w = tid >> 6, lane = tid & 63, l15 = lane & 15, g = lane >> 4;
  int blk = blockIdx.x;
  int bh = blk >> 5, c = blk & 31;
  float km = dec_f32(*kmaxp);
  const uint4* kh4 = reinterpret_cast<const uint4*>(khb);
  const uint4* pj4 = reinterpret_cast<const uint4*>(projb);
  const uint4* vTu = reinterpret_cast<const uint4*>(vTb);
  unsigned* kLw = kL + w * 128 * 33;
  const unsigned short* kL16w = reinterpret_cast<const unsigned short*>(kLw);

  uint4 kf0[8], kf1[8];
  float nbk[8];
  #pragma unroll
  for (int jt = 0; jt < 8; ++jt){
    size_t jrow = (size_t)bh * LL + c * CC + jt * 16 + l15;
    kf0[jt] = kh4[jrow * 8 + g];
    kf1[jt] = kh4[jrow * 8 + 4 + g];
    nbk[jt] = -fmaf(fmaf(DIAGC, rsk[jrow], km), L2E, 4.0f);
  }
  #pragma unroll
  for (int mt = 0; mt < 4; ++mt){
    int mrow = w * 64 + mt * 16 + l15;
    uint4 a0 = pj4[(size_t)mrow * 8 + g];
    uint4 a1 = pj4[(size_t)mrow * 8 + 4 + g];
    #pragma unroll
    for (int jt = 0; jt < 8; ++jt){
      f32x4 acc = {0.f, 0.f, 0.f, 0.f};
      acc = __builtin_amdgcn_mfma_f32_16x16x32_bf16(asb(a0), asb(kf0[jt]), acc, 0, 0, 0);
      acc = __builtin_amdgcn_mfma_f32_16x16x32_bf16(asb(a1), asb(kf1[jt]), acc, 0, 0, 0);
      int dwi = (jt * 16 + l15) * 33 + mt * 8 + g * 2;
      kLw[dwi]     = bfpair(pexp(acc[0], nbk[jt]), pexp(acc[1], nbk[jt]));
      kLw[dwi + 1] = bfpair(pexp(acc[2], nbk[jt]), pexp(acc[3], nbk[jt]));
    }
  }

  uint4 vf[4][4];
  #pragma unroll
  for (int dt = 0; dt < 4; ++dt)
    #pragma unroll
    for (int ks = 0; ks < 4; ++ks)
      vf[dt][ks] = vTu[((size_t)(bh * DD + dt * 16 + l15)) * 512 + c * 16 + ks * 4 + g];

  uint4 zero4 = {0u, 0u, 0u, 0u};
  uint4 ones4 = {0x3F803F80u, 0x3F803F80u, 0x3F803F80u, 0x3F803F80u};
  uint4 onesf = (l15 == 0) ? ones4 : zero4;

  #pragma unroll
  for (int mtr = 0; mtr < 4; ++mtr){
    f32x4 acc[4];
    #pragma unroll
    for (int dt = 0; dt < 4; ++dt) acc[dt] = (f32x4){0.f, 0.f, 0.f, 0.f};
    f32x4 accz = {0.f, 0.f, 0.f, 0.f};
    #pragma unroll
    for (int ks = 0; ks < 4; ++ks){
      PK8 p;
      #pragma unroll
      for (int e = 0; e < 8; ++e)
        p.s[e] = kL16w[(ks * 32 + g * 8 + e) * 66 + mtr * 16 + l15];
      bf16x8 kfb = asb(p.u);
      #pragma unroll
      for (int dt = 0; dt < 4; ++dt)
        acc[dt] = __builtin_amdgcn_mfma_f32_16x16x32_bf16(kfb, asb(vf[dt][ks]), acc[dt], 0, 0, 0);
      accz = __builtin_amdgcn_mfma_f32_16x16x32_bf16(kfb, asb(onesf), accz, 0, 0, 0);
    }
    int m0 = w * 64 + mtr * 16;
    #pragma unroll
    for (int dt = 0; dt < 4; ++dt){
      ushort4 pk;
      pk.x = f2bf(acc[dt][0]); pk.y = f2bf(acc[dt][1]);
      pk.z = f2bf(acc[dt][2]); pk.w = f2bf(acc[dt][3]);
      *reinterpret_cast<ushort4*>(SpT + ((size_t)blk * DD + dt * 16 + l15) * MM + m0 + g * 4) = pk;
    }
    if (l15 == 0){
      float4 o; o.x = accz[0]; o.y = accz[1]; o.z = accz[2]; o.w = accz[3];
      *reinterpret_cast<float4*>(zf + (size_t)blk * MM + m0 + g * 4) = o;
    }
  }
}

// ---------------- K4: merged exclusive prefix (S planes x4-vec + z), x4 unroll ---------
__global__ __launch_bounds__(256) void k_prefix(unsigned short* __restrict__ buf,
                                                const float* __restrict__ zf,
                                                unsigned short* __restrict__ zb){
  int bid = blockIdx.x, tid = threadIdx.x;
  if (bid < 512){
    const int per4 = (DD * MM) / 4;            // 4096 uint2-groups per plane
    int idx = bid * 256 + tid;
    int bh = idx / per4, r4 = idx - bh * per4;
    float run[4];
    #pragma unroll
    for (int e = 0; e < 4; ++e) run[e] = 0.f;
    #pragma unroll 4
    for (int c = 0; c < NCH; ++c){
      size_t a = (((size_t)bh * NCH + c) * (DD * MM)) >> 2;
      uint2* p = reinterpret_cast<uint2*>(buf) + a + r4;
      uint2 v = *p;
      PK4 t; t.u = v;
      PK4 o;
      #pragma unroll
      for (int e = 0; e < 4; ++e){
        o.s[e] = f2bf(run[e]);
        run[e] += bfl((unsigned)t.s[e]);
      }
      *p = o.u;
    }
  } else {
    const int per8 = MM / 8;
    int idx = (bid - 512) * 256 + tid;
    int bh = idx / per8, r8 = idx - bh * per8;
    float run[8];
    #pragma unroll
    for (int e = 0; e < 8; ++e) run[e] = 0.f;
    #pragma unroll 4
    for (int c = 0; c < NCH; ++c){
      size_t base = ((size_t)bh * NCH + c) * MM + r8 * 8;
      float4 v0 = *reinterpret_cast<const float4*>(zf + base);
      float4 v1 = *reinterpret_cast<const float4*>(zf + base + 4);
      PK8 o;
      #pragma unroll
      for (int e = 0; e < 8; ++e) o.s[e] = f2bf(run[e]);
      run[0] += v0.x; run[1] += v0.y; run[2] += v0.z; run[3] += v0.w;
      run[4] += v1.x; run[5] += v1.y; run[6] += v1.z; run[7] += v1.w;
      *reinterpret_cast<uint4*>(zb + base) = o.u;
    }
  }
}

// ---------------- K5: chunk causal attention (mt-outer A, merged-t B, vf hoist) --------
__global__ __launch_bounds__(256, 2) void k_cattn12(const unsigned short* __restrict__ qhb,
                                                    const unsigned short* __restrict__ khb,
                                                    const unsigned short* __restrict__ projb,
                                                    const float* __restrict__ rsq,
                                                    const float* __restrict__ rsk,
                                                    const unsigned* __restrict__ kmaxp,
                                                    const unsigned short* __restrict__ vTb,
                                                    const unsigned short* __restrict__ Spb,
                                                    const unsigned short* __restrict__ zb,
                                                    unsigned short* __restrict__ attnb){
  __shared__ unsigned LDSU[20480];   // 80 KiB
  char* lds = reinterpret_cast<char*>(LDSU);
  int tid = threadIdx.x;
  int w = tid >> 6, lane = tid & 63, l15 = lane & 15, g = lane >> 4;
  int blk = blockIdx.x;
  int bh = blk >> 5, c = blk & 31;
  int b = bh >> 3, h = bh & 7;
  size_t grow0 = (size_t)bh * LL + c * CC;
  float km = dec_f32(*kmaxp);
  const uint4* qh4 = reinterpret_cast<const uint4*>(qhb);
  const uint4* kh4 = reinterpret_cast<const uint4*>(khb);
  const uint4* pj4 = reinterpret_cast<const uint4*>(projb);
  const uint4* vTu = reinterpret_cast<const uint4*>(vTb);
  const uint4* Spu = reinterpret_cast<const uint4*>(Spb);
  const uint4* zbu = reinterpret_cast<const uint4*>(zb);
  uint4 zero4 = {0u, 0u, 0u, 0u};
  uint4 ones4 = {0x3F803F80u, 0x3F803F80u, 0x3F803F80u, 0x3F803F80u};
  int swz = (l15 & 7) << 4;

  // ---- A: phi(k), mt-outer: wave w owns m-range [w*64, w*64+64) for all j ----
  {
    uint4 kf0[8], kf1[8];
    float nbk[8];
    #pragma unroll
    for (int jt = 0; jt < 8; ++jt){
      size_t jrow = grow0 + jt * 16 + l15;
      kf0[jt] = kh4[jrow * 8 + g];
      kf1[jt] = kh4[jrow * 8 + 4 + g];
      nbk[jt] = -fmaf(fmaf(DIAGC, rsk[jrow], km), L2E, 4.0f);
    }
    #pragma unroll
    for (int mt = 0; mt < 4; ++mt){
      int mrow = w * 64 + mt * 16 + l15;
      uint4 a0 = pj4[(size_t)mrow * 8 + g];
      uint4 a1 = pj4[(size_t)mrow * 8 + 4 + g];
      #pragma unroll
      for (int jt = 0; jt < 8; ++jt){
        int jr = jt * 16 + l15;
        f32x4 acc = {0.f, 0.f, 0.f, 0.f};
        acc = __builtin_amdgcn_mfma_f32_16x16x32_bf16(asb(a0), asb(kf0[jt]), acc, 0, 0, 0);
        acc = __builtin_amdgcn_mfma_f32_16x16x32_bf16(asb(a1), asb(kf1[jt]), acc, 0, 0, 0);
        uint2 u;
        u.x = bfpair(pexp(acc[0], nbk[jt]), pexp(acc[1], nbk[jt]));
        u.y = bfpair(pexp(acc[2], nbk[jt]), pexp(acc[3], nbk[jt]));
        int byte = jr * 512 + ((w * 128 + mt * 32 + g * 8) ^ ((jr & 7) << 4));
        *reinterpret_cast<uint2*>(lds + byte) = u;
      }
    }
  }

  // ---- B: phi(q) for both i-tiles, merged mt loop ----
  int its[2] = { w, 7 - w };
  int swb = 65536 + w * 4096 + l15 * 256;
  uint4 qf[2][8];
  f32x4 acc[2][5];
  {
    size_t irow0 = grow0 + its[0] * 16 + l15;
    size_t irow1 = grow0 + its[1] * 16 + l15;
    uint4 qb0_0 = qh4[irow0 * 8 + g];
    uint4 qb1_0 = qh4[irow0 * 8 + 4 + g];
    uint4 qb0_1 = qh4[irow1 * 8 + g];
    uint4 qb1_1 = qh4[irow1 * 8 + 4 + g];
    f32x4 aq0[16], aq1[16];
    #pragma unroll
    for (int mt = 0; mt < 16; ++mt){
      uint4 a0 = pj4[(size_t)(mt * 16 + l15) * 8 + g];
      uint4 a1 = pj4[(size_t)(mt * 16 + l15) * 8 + 4 + g];
      f32x4 x0 = {0.f, 0.f, 0.f, 0.f};
      x0 = __builtin_amdgcn_mfma_f32_16x16x32_bf16(asb(a0), asb(qb0_0), x0, 0, 0, 0);
      aq0[mt] = __builtin_amdgcn_mfma_f32_16x16x32_bf16(asb(a1), asb(qb1_0), x0, 0, 0, 0);
      f32x4 x1 = {0.f, 0.f, 0.f, 0.f};
      x1 = __builtin_amdgcn_mfma_f32_16x16x32_bf16(asb(a0), asb(qb0_1), x1, 0, 0, 0);
      aq1[mt] = __builtin_amdgcn_mfma_f32_16x16x32_bf16(asb(a1), asb(qb1_1), x1, 0, 0, 0);
    }
    // t=0
    {
      float mx = -3.0e38f;
      #pragma unroll
      for (int mt = 0; mt < 16; ++mt)
        mx = fmaxf(mx, fmaxf(fmaxf(aq0[mt][0], aq0[mt][1]), fmaxf(aq0[mt][2], aq0[mt][3])));
      mx = fmaxf(mx, __shfl_xor(mx, 16, 64));
      mx = fmaxf(mx, __shfl_xor(mx, 32, 64));
      float nb = -fmaf(fmaf(DIAGC, rsq[irow0], mx), L2E, 4.0f);
      #pragma unroll
      for (int half = 0; half < 2; ++half){
        #pragma unroll
        for (int mt = 0; mt < 8; ++mt){
          f32x4 a = aq0[half * 8 + mt];
          uint2 u;
          u.x = bfpair(pexp(a[0], nb), pexp(a[1], nb));
          u.y = bfpair(pexp(a[2], nb), pexp(a[3], nb));
          int byte = swb + ((mt * 32 + g * 8) ^ swz);
          *reinterpret_cast<uint2*>(lds + byte) = u;
        }
        #pragma unroll
        for (int ks = 0; ks < 4; ++ks){
          int byte = swb + ((ks * 64 + g * 16) ^ swz);
          qf[0][half * 4 + ks] = *reinterpret_cast<const uint4*>(lds + byte);
        }
      }
    }
    // t=1
    {
      float mx = -3.0e38f;
      #pragma unroll
      for (int mt = 0; mt < 16; ++mt)
        mx = fmaxf(mx, fmaxf(fmaxf(aq1[mt][0], aq1[mt][1]), fmaxf(aq1[mt][2], aq1[mt][3])));
      mx = fmaxf(mx, __shfl_xor(mx, 16, 64));
      mx = fmaxf(mx, __shfl_xor(mx, 32, 64));
      float nb = -fmaf(fmaf(DIAGC, rsq[irow1], mx), L2E, 4.0f);
      #pragma unroll
      for (int half = 0; half < 2; ++half){
        #pragma unroll
        for (int mt = 0; mt < 8; ++mt){
          f32x4 a = aq1[half * 8 + mt];
          uint2 u;
          u.x = bfpair(pexp(a[0], nb), pexp(a[1], nb));
          u.y = bfpair(pexp(a[2], nb), pexp(a[3], nb));
          int byte = swb + ((mt * 32 + g * 8) ^ swz);
          *reinterpret_cast<uint2*>(lds + byte) = u;
        }
        #pragma unroll
        for (int ks = 0; ks < 4; ++ks){
          int byte = swb + ((ks * 64 + g * 16) ^ swz);
          qf[1][half * 4 + ks] = *reinterpret_cast<const uint4*>(lds + byte);
        }
      }
    }
  }

  // ---- B2: shared-Sp prefix pass ----
  #pragma unroll
  for (int t = 0; t < 2; ++t)
    #pragma unroll
    for (int a5 = 0; a5 < 5; ++a5) acc[t][a5] = (f32x4){0.f, 0.f, 0.f, 0.f};
  #pragma unroll
  for (int ks = 0; ks < 8; ++ks){
    bf16x8 q0 = asb(qf[0][ks]);
    bf16x8 q1 = asb(qf[1][ks]);
    #pragma unroll
    for (int dt = 0; dt < 4; ++dt){
      uint4 spf = Spu[((size_t)blk * DD + dt * 16 + l15) * 32 + ks * 4 + g];
      acc[0][dt] = __builtin_amdgcn_mfma_f32_16x16x32_bf16(asb(spf), q0, acc[0][dt], 0, 0, 0);
      acc[1][dt] = __builtin_amdgcn_mfma_f32_16x16x32_bf16(asb(spf), q1, acc[1][dt], 0, 0, 0);
    }
    uint4 zfr = (l15 == 0) ? zbu[blk * 32 + ks * 4 + g] : zero4;
    acc[0][4] = __builtin_amdgcn_mfma_f32_16x16x32_bf16(asb(zfr), q0, acc[0][4], 0, 0, 0);
    acc[1][4] = __builtin_amdgcn_mfma_f32_16x16x32_bf16(asb(zfr), q1, acc[1][4], 0, 0, 0);
  }

  // hoist PV V-fragments (t-independent; reused by both i-tiles)
  uint4 vf[4][4];
  #pragma unroll
  for (int dt = 0; dt < 4; ++dt)
    #pragma unroll
    for (int ks = 0; ks < 4; ++ks)
      vf[dt][ks] = vTu[((size_t)(bh * DD + dt * 16 + l15)) * 512 + c * 16 + ks * 4 + g];
  __syncthreads();

  // ---- C: scores (split accumulators) + PV + out, both i-tiles ----
  #pragma unroll
  for (int t = 0; t < 2; ++t){
    int it = its[t];
    int i = it * 16 + l15;
    int jtmax = it | 1;
    #pragma unroll
    for (int jt = 0; jt < 8; ++jt){
      if (jt <= jtmax){   // wave-uniform
        f32x4 sa0 = {0.f, 0.f, 0.f, 0.f};
        f32x4 sa1 = {0.f, 0.f, 0.f, 0.f};
        int jr = jt * 16 + l15;
        __builtin_amdgcn_s_setprio(1);
        #pragma unroll
        for (int ks = 0; ks < 4; ++ks){
          int byte0 = jr * 512 + (((2 * ks) * 64 + g * 16) ^ ((jr & 7) << 4));
          int byte1 = jr * 512 + (((2 * ks + 1) * 64 + g * 16) ^ ((jr & 7) << 4));
          uint4 kfu0 = *reinterpret_cast<const uint4*>(lds + byte0);
          uint4 kfu1 = *reinterpret_cast<const uint4*>(lds + byte1);
          sa0 = __builtin_amdgcn_mfma_f32_16x16x32_bf16(asb(kfu0), asb(qf[t][2 * ks]), sa0, 0, 0, 0);
          sa1 = __builtin_amdgcn_mfma_f32_16x16x32_bf16(asb(kfu1), asb(qf[t][2 * ks + 1]), sa1, 0, 0, 0);
        }
        __builtin_amdgcn_s_setprio(0);
        f32x4 sa = sa0 + sa1;
        int jb = jt * 16 + g * 4;
        uint2 u;
        u.x = bfpair((jb + 0 <= i) ? sa[0] : 0.f, (jb + 1 <= i) ? sa[1] : 0.f);
        u.y = bfpair((jb + 2 <= i) ? sa[2] : 0.f, (jb + 3 <= i) ? sa[3] : 0.f);
        int byte = swb + ((jt * 32 + g * 8) ^ swz);
        *reinterpret_cast<uint2*>(lds + byte) = u;
      }
    }
    int ksmax = it >> 1;
    #pragma unroll
    for (int ks = 0; ks < 4; ++ks){
      if (ks <= ksmax){   // wave-uniform
        int byte = swb + ((ks * 64 + g * 16) ^ swz);
        uint4 sfu = *reinterpret_cast<const uint4*>(lds + byte);
        bf16x8 sf = asb(sfu);
        __builtin_amdgcn_s_setprio(1);
        #pragma unroll
        for (int dt = 0; dt < 4; ++dt)
          acc[t][dt] = __builtin_amdgcn_mfma_f32_16x16x32_bf16(asb(vf[dt][ks]), sf, acc[t][dt], 0, 0, 0);
        uint4 of = (l15 == 0) ? ones4 : zero4;
        acc[t][4] = __builtin_amdgcn_mfma_f32_16x16x32_bf16(asb(of), sf, acc[t][4], 0, 0, 0);
        __builtin_amdgcn_s_setprio(0);
      }
    }
    float den = __shfl(acc[t][4][0], l15, 64);
    float inv = 1.f / den;
    size_t obase = ((size_t)(b * LL + c * CC + i)) * EE + h * DD;
    #pragma unroll
    for (int dt = 0; dt < 4; ++dt){
      ushort4 pk;
      pk.x = f2bf(acc[t][dt][0] * inv); pk.y = f2bf(acc[t][dt][1] * inv);
      pk.z = f2bf(acc[t][dt][2] * inv); pk.w = f2bf(acc[t][dt][3] * inv);
      *reinterpret_cast<ushort4*>(attnb + obase + dt * 16 + g * 4) = pk;
    }
  }
}

// ---------------- K6: MFMA out-proj v2 — LDS-staged Woutb panel + pipelined ks ----------
__global__ __launch_bounds__(256, 2) void k_proj_M2(const unsigned short* __restrict__ attnb,
                                                    const unsigned short* __restrict__ Woutb,
                                                    const float* __restrict__ bout,
                                                    float* __restrict__ out){
  __shared__ unsigned short Wl[64 * 512];   // 64KB: 8 ktiles of 64x64, swizzled
  int tid = threadIdx.x;
  int w = tid >> 6, lane = tid & 63, l15 = lane & 15, g = lane >> 4;
  int rb = blockIdx.x & 63, eb = blockIdx.x >> 6;   // eb-siblings share an XCD (64%8==0)
  int r0 = rb * 256, e0 = eb * 64;
  const uint4* at4 = reinterpret_cast<const uint4*>(attnb);
  const uint4* Wo4 = reinterpret_cast<const uint4*>(Woutb);
  for (int idx = tid; idx < 4096; idx += 256){
    int row = idx >> 6, rest = idx & 63, kt = rest >> 3, ch = rest & 7;
    uint4 v = Wo4[(size_t)(e0 + row) * 64 + kt * 8 + ch];
    int byte = kt * 8192 + row * 128 + ((ch * 16) ^ ((row & 7) << 4));
    *reinterpret_cast<uint4*>(reinterpret_cast<char*>(Wl) + byte) = v;
  }
  __syncthreads();
  const char* Wc = reinterpret_cast<const char*>(Wl);
  f32x4 acc[4][4];   // [rt][ct]
  #pragma unroll
  for (int rt = 0; rt < 4; ++rt)
    #pragma unroll
    for (int ct = 0; ct < 4; ++ct) acc[rt][ct] = (f32x4){0.f, 0.f, 0.f, 0.f};
  size_t rbase = (size_t)(r0 + w * 64 + l15) * 64;   // uint4 units (EE*2B/16)
  #pragma unroll 4
  for (int ks = 0; ks < 16; ++ks){
    uint4 bfr[4];
    #pragma unroll
    for (int rt = 0; rt < 4; ++rt)
      bfr[rt] = at4[rbase + (size_t)rt * 16 * 64 + ks * 4 + g];
    int kt = ks >> 1, k2 = ks & 1;
    #pragma unroll
    for (int ct = 0; ct < 4; ++ct){
      int row = ct * 16 + l15;
      int byte = kt * 8192 + row * 128 + ((k2 * 64 + g * 16) ^ ((row & 7) << 4));
      uint4 af = *reinterpret_cast<const uint4*>(Wc + byte);
      bf16x8 afb = asb(af);
      #pragma unroll
      for (int rt = 0; rt < 4; ++rt)
        acc[rt][ct] = __builtin_amdgcn_mfma_f32_16x16x32_bf16(afb, asb(bfr[rt]), acc[rt][ct], 0, 0, 0);
    }
  }
  #pragma unroll
  for (int ct = 0; ct < 4; ++ct){
    int e = e0 + ct * 16 + g * 4;
    float4 bo = *reinterpret_cast<const float4*>(bout + e);
    #pragma unroll
    for (int rt = 0; rt < 4; ++rt){
      int r = r0 + w * 64 + rt * 16 + l15;
      float4 o;
      o.x = acc[rt][ct][0] + bo.x; o.y = acc[rt][ct][1] + bo.y;
      o.z = acc[rt][ct][2] + bo.z; o.w = acc[rt][ct][3] + bo.w;
      *reinterpret_cast<float4*>(out + (size_t)r * EE + e) = o;
    }
  }
}

extern "C" void kernel_launch(void* const* d_in, const int* in_sizes, int n_in,
                              void* d_out, int out_size, void* d_ws, size_t ws_size,
                              hipStream_t stream){
  const float* queries = (const float*)d_in[0];
  const float* keys    = (const float*)d_in[1];
  const float* values  = (const float*)d_in[2];
  const float* Wq      = (const float*)d_in[3];
  const float* Wk      = (const float*)d_in[4];
  const float* Wv      = (const float*)d_in[5];
  const float* Wout    = (const float*)d_in[6];
  const float* bout    = (const float*)d_in[7];
  const float* proj    = (const float*)d_in[8];

  // workspace layout (~104 MB, no aliasing)
  char* ws = (char*)d_ws;
  unsigned short* qhb  = (unsigned short*)(ws + 0);           // 16.8M [BH,L,D]
  unsigned short* khb  = (unsigned short*)(ws + 16777216);    // 16.8M
  unsigned short* vTb  = (unsigned short*)(ws + 33554432);    // 16.8M [BH,D,L]
  unsigned short* SpT  = (unsigned short*)(ws + 50331648);    // 33.5M [BH,NCH,D,M]
  unsigned short* attnb= (unsigned short*)(ws + 83886080);    // 16.8M [B,L,E]
  float*          zfbuf= (float*)(ws + 100663296);            // 1.0M
  unsigned short* zb   = (unsigned short*)(ws + 101711872);   // 0.5M
  float*          rsq  = (float*)(ws + 102236160);            // 0.5M
  float*          rsk  = (float*)(ws + 102760448);            // 0.5M
  unsigned short* Woutb= (unsigned short*)(ws + 103284736);   // 0.5M
  unsigned short* projb= (unsigned short*)(ws + 103809024);   // 32K  [M,D] bf16 (DN folded)
  unsigned short* PWb  = (unsigned short*)(ws + 103841792);   // 32K  [M,D] bf16 (DN*proj@Wk)
  unsigned*       kmax = (unsigned*)(ws + 103874560);         // 4
  float*          out  = (float*)d_out;

  hipMemsetAsync(kmax, 0, 4, stream);

  k_cvt<<<dim3(608), dim3(256), 0, stream>>>(Wout, Woutb, proj, projb, Wk, PWb);

  k_qkv<<<dim3(BHN * 32), dim3(256), 0, stream>>>(queries, keys, values, Wq, Wk, Wv, PWb,
                                                  qhb, khb, vTb, rsq, rsk, kmax);

  k_chunkKV6<<<dim3(BHN * NCH), dim3(256), 0, stream>>>(khb, projb, rsk, kmax, vTb, SpT, zfbuf);

  k_prefix<<<dim3(516), dim3(256), 0, stream>>>(SpT, zfbuf, zb);

  k_cattn12<<<dim3(BHN * NCH), dim3(256), 0, stream>>>(qhb, khb, projb, rsq, rsk, kmax,
                                                       vTb, SpT, zb, attnb);

  k_proj_M2<<<dim3(512), dim3(256), 0, stream>>>(attnb, Woutb, bout, out);
}

// Round 17
// 189.517 us; speedup vs baseline: 1.0858x; 1.0858x over previous
//
#include <hip/hip_runtime.h>
#include <hip/hip_bf16.h>

// Performer (FAVOR+) causal linear self-attention, MI355X round 16.
// B=4 L=4096 E=512 H=8 D=64 M=256 chunk=128.
// Round 16: revert to the round-12 configuration verbatim (measured best,
// 189.98us). Rounds 13-15's micro-mutations (cvt_pk asm, setprio, vf-hoist,
// kmax-fold, prefix unroll) were neutral or regressions; this restores the
// empirically fastest known-good pipeline.

#define BB 4
#define LL 4096
#define EE 512
#define HH 8
#define DD 64
#define MM 256
#define CC 128
#define NCH 32   // L / CC
#define BHN 32   // B * H

constexpr float DN    = 0.35355339059327373f; // 64^-0.25
constexpr float DIAGC = 0.0625f;              // 0.5 * dn^2
constexpr float RATIO = 0.0625f;              // 256^-0.5
constexpr float EPSV  = 1e-4f;
constexpr float L2E   = 1.4426950408889634f;  // log2(e)
constexpr float CEPS  = 6.25e-6f;             // RATIO*EPSV

typedef __attribute__((ext_vector_type(8))) short bf16x8;
typedef __attribute__((ext_vector_type(4))) float f32x4;
union FU { uint4 u; bf16x8 b; };
__device__ __forceinline__ bf16x8 asb(uint4 u){ FU f; f.u = u; return f.b; }
union PK8 { unsigned short s[8]; uint4 u; };
union PK4 { unsigned short s[4]; uint2 u; };

__device__ __forceinline__ unsigned short f2bf(float f){
  unsigned u = __float_as_uint(f);
  u = u + 0x7FFFu + ((u >> 16) & 1u);   // RTNE
  return (unsigned short)(u >> 16);
}
__device__ __forceinline__ float bfl(unsigned u){ return __uint_as_float(u << 16); }
__device__ __forceinline__ unsigned bfpair(float lo, float hi){
  return (unsigned)f2bf(lo) | ((unsigned)f2bf(hi) << 16);
}
// RATIO*(exp(x - bs) + EPSV) == exp2(x*L2E + nb) + CEPS with nb = -(bs*L2E + 4)
__device__ __forceinline__ float pexp(float x, float nb){
  return exp2f(fmaf(x, L2E, nb)) + CEPS;
}
__device__ __forceinline__ unsigned enc_f32(float f){
  unsigned u = __float_as_uint(f);
  return (u & 0x80000000u) ? ~u : (u | 0x80000000u);
}
__device__ __forceinline__ float dec_f32(unsigned u){
  unsigned v = (u & 0x80000000u) ? (u & 0x7FFFFFFFu) : ~u;
  return __uint_as_float(v);
}
__device__ __forceinline__ uint4 pack8(float4 a, float4 b){
  PK8 p;
  p.s[0] = f2bf(a.x); p.s[1] = f2bf(a.y); p.s[2] = f2bf(a.z); p.s[3] = f2bf(a.w);
  p.s[4] = f2bf(b.x); p.s[5] = f2bf(b.y); p.s[6] = f2bf(b.z); p.s[7] = f2bf(b.w);
  return p.u;
}

// ---------------- K0: merged Wout + proj f32 -> bf16 ----------------
__global__ __launch_bounds__(256) void k_cvt(const float* __restrict__ Wout,
                                             unsigned short* __restrict__ Woutb,
                                             const float* __restrict__ proj,
                                             unsigned short* __restrict__ projb){
  int bid = blockIdx.x, tid = threadIdx.x;
  if (bid < 512){
    int idx = bid * 256 + tid;
    float2 v = reinterpret_cast<const float2*>(Wout)[idx];
    reinterpret_cast<unsigned*>(Woutb)[idx] = bfpair(v.x, v.y);
  } else {
    int idx = (bid - 512) * 256 + tid;
    float2 v = reinterpret_cast<const float2*>(proj)[idx];
    reinterpret_cast<unsigned*>(projb)[idx] = bfpair(v.x * DN, v.y * DN);
  }
}

// ---------------- K1: fused MFMA qkv transform ----------------
__global__ __launch_bounds__(256) void k_qkv(const float* __restrict__ xq,
                                             const float* __restrict__ xk,
                                             const float* __restrict__ xv,
                                             const float* __restrict__ Wq,
                                             const float* __restrict__ Wk,
                                             const float* __restrict__ Wv,
                                             unsigned short* __restrict__ qhb,
                                             unsigned short* __restrict__ khb,
                                             unsigned short* __restrict__ vTb,
                                             float* __restrict__ rsq,
                                             float* __restrict__ rsk){
  __shared__ unsigned short Wl[3 * 64 * 64];   // 24KB swizzled bf16
  int tid = threadIdx.x;
  for (int idx = tid; idx < 3 * 64 * 8; idx += 256){
    int sel = idx >> 9, rem = idx & 511, row = rem >> 3, ch = rem & 7;
    const float* Wp = sel == 0 ? Wq : (sel == 1 ? Wk : Wv);
    const float4* w4 = reinterpret_cast<const float4*>(Wp) + row * 16 + ch * 2;
    int byte = sel * 8192 + row * 128 + ((ch * 16) ^ ((row & 7) << 4));
    *reinterpret_cast<uint4*>(reinterpret_cast<char*>(Wl) + byte) = pack8(w4[0], w4[1]);
  }
  __syncthreads();
  int w = tid >> 6, lane = tid & 63, l15 = lane & 15, g = lane >> 4;
  int bh = blockIdx.x >> 5, lb = blockIdx.x & 31;
  int b = bh >> 3, h = bh & 7;
  const char* Wc = reinterpret_cast<const char*>(Wl);
  #pragma unroll
  for (int tt = 0; tt < 2; ++tt){
    int lt = w * 2 + tt;
    int l = lb * 128 + lt * 16 + l15;
    size_t xoff = ((size_t)(b * LL + l)) * EE + h * DD;
    const float4* q4 = reinterpret_cast<const float4*>(xq + xoff);
    const float4* k4 = reinterpret_cast<const float4*>(xk + xoff);
    const float4* v4 = reinterpret_cast<const float4*>(xv + xoff);
    uint4 fq[2], fk[2], fv[2];
    #pragma unroll
    for (int ks = 0; ks < 2; ++ks){
      int fi = ks * 8 + g * 2;
      fq[ks] = pack8(q4[fi], q4[fi + 1]);
      fk[ks] = pack8(k4[fi], k4[fi + 1]);
      fv[ks] = pack8(v4[fi], v4[fi + 1]);
    }
    size_t grow = (size_t)bh * LL + l;
    // ---- q ----
    {
      float ss = 0.f;
      #pragma unroll
      for (int dt = 0; dt < 4; ++dt){
        int row = dt * 16 + l15;
        f32x4 acc = {0.f, 0.f, 0.f, 0.f};
        #pragma unroll
        for (int ks = 0; ks < 2; ++ks){
          int byte = 0 * 8192 + row * 128 + ((ks * 64 + g * 16) ^ ((row & 7) << 4));
          uint4 wf = *reinterpret_cast<const uint4*>(Wc + byte);
          acc = __builtin_amdgcn_mfma_f32_16x16x32_bf16(asb(wf), asb(fq[ks]), acc, 0, 0, 0);
        }
        ss += acc[0]*acc[0] + acc[1]*acc[1] + acc[2]*acc[2] + acc[3]*acc[3];
        ushort4 pk;
        pk.x = f2bf(acc[0]); pk.y = f2bf(acc[1]); pk.z = f2bf(acc[2]); pk.w = f2bf(acc[3]);
        *reinterpret_cast<ushort4*>(qhb + grow * 64 + dt * 16 + g * 4) = pk;
      }
      ss += __shfl_xor(ss, 16, 64);
      ss += __shfl_xor(ss, 32, 64);
      if (g == 0) rsq[grow] = ss;
    }
    // ---- k ----
    {
      float ss = 0.f;
      #pragma unroll
      for (int dt = 0; dt < 4; ++dt){
        int row = dt * 16 + l15;
        f32x4 acc = {0.f, 0.f, 0.f, 0.f};
        #pragma unroll
        for (int ks = 0; ks < 2; ++ks){
          int byte = 1 * 8192 + row * 128 + ((ks * 64 + g * 16) ^ ((row & 7) << 4));
          uint4 wf = *reinterpret_cast<const uint4*>(Wc + byte);
          acc = __builtin_amdgcn_mfma_f32_16x16x32_bf16(asb(wf), asb(fk[ks]), acc, 0, 0, 0);
        }
        ss += acc[0]*acc[0] + acc[1]*acc[1] + acc[2]*acc[2] + acc[3]*acc[3];
        ushort4 pk;
        pk.x = f2bf(acc[0]); pk.y = f2bf(acc[1]); pk.z = f2bf(acc[2]); pk.w = f2bf(acc[3]);
        *reinterpret_cast<ushort4*>(khb + grow * 64 + dt * 16 + g * 4) = pk;
      }
      ss += __shfl_xor(ss, 16, 64);
      ss += __shfl_xor(ss, 32, 64);
      if (g == 0) rsk[grow] = ss;
    }
    // ---- v transposed ----
    #pragma unroll
    for (int dt = 0; dt < 4; ++dt){
      int row = dt * 16 + l15;
      f32x4 acc = {0.f, 0.f, 0.f, 0.f};
      #pragma unroll
      for (int ks = 0; ks < 2; ++ks){
        int byte = 2 * 8192 + row * 128 + ((ks * 64 + g * 16) ^ ((row & 7) << 4));
        uint4 wf = *reinterpret_cast<const uint4*>(Wc + byte);
        acc = __builtin_amdgcn_mfma_f32_16x16x32_bf16(asb(fv[ks]), asb(wf), acc, 0, 0, 0);
      }
      ushort4 pk;
      pk.x = f2bf(acc[0]); pk.y = f2bf(acc[1]); pk.z = f2bf(acc[2]); pk.w = f2bf(acc[3]);
      *reinterpret_cast<ushort4*>(vTb + ((size_t)(bh * DD + dt * 16 + l15)) * LL
                                  + lb * 128 + lt * 16 + g * 4) = pk;
    }
  }
}

// ---------------- K2: global max of xd(k) — proj-hoisted, 1 atomic/block ----------------
__global__ __launch_bounds__(256) void k_kmaxM(const unsigned short* __restrict__ khb,
                                               const unsigned short* __restrict__ projb,
                                               unsigned* __restrict__ kmaxp){
  __shared__ float red[4];
  int tid = threadIdx.x;
  int w = tid >> 6, lane = tid & 63, l15 = lane & 15, g = lane >> 4;
  const uint4* kh4 = reinterpret_cast<const uint4*>(khb);
  const uint4* pj4 = reinterpret_cast<const uint4*>(projb);
  uint4 pa0[16], pa1[16];
  #pragma unroll
  for (int mt = 0; mt < 16; ++mt){
    pa0[mt] = pj4[(size_t)(mt * 16 + l15) * 8 + g];
    pa1[mt] = pj4[(size_t)(mt * 16 + l15) * 8 + 4 + g];
  }
  float mx = -3.0e38f;
  #pragma unroll
  for (int it = 0; it < 8; ++it){
    int rb = blockIdx.x * 4 + w + it * 1024;
    size_t row = (size_t)rb * 16 + l15;
    uint4 kb0 = kh4[row * 8 + g];
    uint4 kb1 = kh4[row * 8 + 4 + g];
    #pragma unroll
    for (int mt = 0; mt < 16; ++mt){
      f32x4 acc = {0.f, 0.f, 0.f, 0.f};
      acc = __builtin_amdgcn_mfma_f32_16x16x32_bf16(asb(pa0[mt]), asb(kb0), acc, 0, 0, 0);
      acc = __builtin_amdgcn_mfma_f32_16x16x32_bf16(asb(pa1[mt]), asb(kb1), acc, 0, 0, 0);
      mx = fmaxf(mx, fmaxf(fmaxf(acc[0], acc[1]), fmaxf(acc[2], acc[3])));
    }
  }
  #pragma unroll
  for (int off = 32; off >= 1; off >>= 1)
    mx = fmaxf(mx, __shfl_xor(mx, off, 64));
  if (lane == 0) red[w] = mx;
  __syncthreads();
  if (tid == 0){
    float m = fmaxf(fmaxf(red[0], red[1]), fmaxf(red[2], red[3]));
    atomicMax(kmaxp, enc_f32(m));   // 256 atomics total
  }
}

// ---------------- K3: per-chunk KV sums, mt-outer phi(k) (load-reuse) ----------------
__global__ __launch_bounds__(256, 2) void k_chunkKV6(const unsigned short* __restrict__ khb,
                                                     const unsigned short* __restrict__ projb,
                                                     const float* __restrict__ rsk,
                                                     const unsigned* __restrict__ kmaxp,
                                                     const unsigned short* __restrict__ vTb,
                                                     unsigned short* __restrict__ SpT,
                                                     float* __restrict__ zf){
  __shared__ unsigned kL[4 * 128 * 33];    // 67.6 KiB, per-wave panels
  int tid = threadIdx.x;
  int w = tid >> 6, lane = tid & 63, l15 = lane & 15, g = lane >> 4;
  int blk = blockIdx.x;
  int bh = blk >> 5, c = blk & 31;
  float km = dec_f32(*kmaxp);
  const uint4* kh4 = reinterpret_cast<const uint4*>(khb);
  const uint4* pj4 = reinterpret_cast<const uint4*>(projb);
  const uint4* vTu = reinterpret_cast<const uint4*>(vTb);
  unsigned* kLw = kL + w * 128 * 33;
  const unsigned short* kL16w = reinterpret_cast<const unsigned short*>(kLw);

  uint4 kf0[8], kf1[8];
  float nbk[8];
  #pragma unroll
  for (int jt = 0; jt < 8; ++jt){
    size_t jrow = (size_t)bh * LL + c * CC + jt * 16 + l15;
    kf0[jt] = kh4[jrow * 8 + g];
    kf1[jt] = kh4[jrow * 8 + 4 + g];
    nbk[jt] = -fmaf(fmaf(DIAGC, rsk[jrow], km), L2E, 4.0f);
  }
  #pragma unroll
  for (int mt = 0; mt < 4; ++mt){
    int mrow = w * 64 + mt * 16 + l15;
    uint4 a0 = pj4[(size_t)mrow * 8 + g];
    uint4 a1 = pj4[(size_t)mrow * 8 + 4 + g];
    #pragma unroll
    for (int jt = 0; jt < 8; ++jt){
      f32x4 acc = {0.f, 0.f, 0.f, 0.f};
      acc = __builtin_amdgcn_mfma_f32_16x16x32_bf16(asb(a0), asb(kf0[jt]), acc, 0, 0, 0);
      acc = __builtin_amdgcn_mfma_f32_16x16x32_bf16(asb(a1), asb(kf1[jt]), acc, 0, 0, 0);
      int dwi = (jt * 16 + l15) * 33 + mt * 8 + g * 2;
      kLw[dwi]     = bfpair(pexp(acc[0], nbk[jt]), pexp(acc[1], nbk[jt]));
      kLw[dwi + 1] = bfpair(pexp(acc[2], nbk[jt]), pexp(acc[3], nbk[jt]));
    }
  }

  uint4 vf[4][4];
  #pragma unroll
  for (int dt = 0; dt < 4; ++dt)
    #pragma unroll
    for (int ks = 0; ks < 4; ++ks)
      vf[dt][ks] = vTu[((size_t)(bh * DD + dt * 16 + l15)) * 512 + c * 16 + ks * 4 + g];

  uint4 zero4 = {0u, 0u, 0u, 0u};
  uint4 ones4 = {0x3F803F80u, 0x3F803F80u, 0x3F803F80u, 0x3F803F80u};
  uint4 onesf = (l15 == 0) ? ones4 : zero4;

  #pragma unroll
  for (int mtr = 0; mtr < 4; ++mtr){
    f32x4 acc[4];
    #pragma unroll
    for (int dt = 0; dt < 4; ++dt) acc[dt] = (f32x4){0.f, 0.f, 0.f, 0.f};
    f32x4 accz = {0.f, 0.f, 0.f, 0.f};
    #pragma unroll
    for (int ks = 0; ks < 4; ++ks){
      PK8 p;
      #pragma unroll
      for (int e = 0; e < 8; ++e)
        p.s[e] = kL16w[(ks * 32 + g * 8 + e) * 66 + mtr * 16 + l15];
      bf16x8 kfb = asb(p.u);
      #pragma unroll
      for (int dt = 0; dt < 4; ++dt)
        acc[dt] = __builtin_amdgcn_mfma_f32_16x16x32_bf16(kfb, asb(vf[dt][ks]), acc[dt], 0, 0, 0);
      accz = __builtin_amdgcn_mfma_f32_16x16x32_bf16(kfb, asb(onesf), accz, 0, 0, 0);
    }
    int m0 = w * 64 + mtr * 16;
    #pragma unroll
    for (int dt = 0; dt < 4; ++dt){
      ushort4 pk;
      pk.x = f2bf(acc[dt][0]); pk.y = f2bf(acc[dt][1]);
      pk.z = f2bf(acc[dt][2]); pk.w = f2bf(acc[dt][3]);
      *reinterpret_cast<ushort4*>(SpT + ((size_t)blk * DD + dt * 16 + l15) * MM + m0 + g * 4) = pk;
    }
    if (l15 == 0){
      float4 o; o.x = accz[0]; o.y = accz[1]; o.z = accz[2]; o.w = accz[3];
      *reinterpret_cast<float4*>(zf + (size_t)blk * MM + m0 + g * 4) = o;
    }
  }
}

// ---------------- K4: merged exclusive prefix (S planes x4-vec + z) ----------------
__global__ __launch_bounds__(256) void k_prefix(unsigned short* __restrict__ buf,
                                                const float* __restrict__ zf,
                                                unsigned short* __restrict__ zb){
  int bid = blockIdx.x, tid = threadIdx.x;
  if (bid < 512){
    const int per4 = (DD * MM) / 4;            // 4096 uint2-groups per plane
    int idx = bid * 256 + tid;
    int bh = idx / per4, r4 = idx - bh * per4;
    float run[4];
    #pragma unroll
    for (int e = 0; e < 4; ++e) run[e] = 0.f;
    for (int c = 0; c < NCH; ++c){
      size_t a = (((size_t)bh * NCH + c) * (DD * MM)) >> 2;
      uint2* p = reinterpret_cast<uint2*>(buf) + a + r4;
      uint2 v = *p;
      PK4 t; t.u = v;
      PK4 o;
      #pragma unroll
      for (int e = 0; e < 4; ++e){
        o.s[e] = f2bf(run[e]);
        run[e] += bfl((unsigned)t.s[e]);
      }
      *p = o.u;
    }
  } else {
    const int per8 = MM / 8;
    int idx = (bid - 512) * 256 + tid;
    int bh = idx / per8, r8 = idx - bh * per8;
    float run[8];
    #pragma unroll
    for (int e = 0; e < 8; ++e) run[e] = 0.f;
    for (int c = 0; c < NCH; ++c){
      size_t base = ((size_t)bh * NCH + c) * MM + r8 * 8;
      float4 v0 = *reinterpret_cast<const float4*>(zf + base);
      float4 v1 = *reinterpret_cast<const float4*>(zf + base + 4);
      PK8 o;
      #pragma unroll
      for (int e = 0; e < 8; ++e) o.s[e] = f2bf(run[e]);
      run[0] += v0.x; run[1] += v0.y; run[2] += v0.z; run[3] += v0.w;
      run[4] += v1.x; run[5] += v1.y; run[6] += v1.z; run[7] += v1.w;
      *reinterpret_cast<uint4*>(zb + base) = o.u;
    }
  }
}

// ---------------- K5: chunk causal attention (mt-outer A, merged-t B) ----------------
__global__ __launch_bounds__(256, 2) void k_cattn10(const unsigned short* __restrict__ qhb,
                                                    const unsigned short* __restrict__ khb,
                                                    const unsigned short* __restrict__ projb,
                                                    const float* __restrict__ rsq,
                                                    const float* __restrict__ rsk,
                                                    const unsigned* __restrict__ kmaxp,
                                                    const unsigned short* __restrict__ vTb,
                                                    const unsigned short* __restrict__ Spb,
                                                    const unsigned short* __restrict__ zb,
                                                    unsigned short* __restrict__ attnb){
  __shared__ unsigned LDSU[20480];   // 80 KiB
  char* lds = reinterpret_cast<char*>(LDSU);
  int tid = threadIdx.x;
  int w = tid >> 6, lane = tid & 63, l15 = lane & 15, g = lane >> 4;
  int blk = blockIdx.x;
  int bh = blk >> 5, c = blk & 31;
  int b = bh >> 3, h = bh & 7;
  size_t grow0 = (size_t)bh * LL + c * CC;
  float km = dec_f32(*kmaxp);
  const uint4* qh4 = reinterpret_cast<const uint4*>(qhb);
  const uint4* kh4 = reinterpret_cast<const uint4*>(khb);
  const uint4* pj4 = reinterpret_cast<const uint4*>(projb);
  const uint4* vTu = reinterpret_cast<const uint4*>(vTb);
  const uint4* Spu = reinterpret_cast<const uint4*>(Spb);
  const uint4* zbu = reinterpret_cast<const uint4*>(zb);
  uint4 zero4 = {0u, 0u, 0u, 0u};
  uint4 ones4 = {0x3F803F80u, 0x3F803F80u, 0x3F803F80u, 0x3F803F80u};
  int swz = (l15 & 7) << 4;

  // ---- A: phi(k), mt-outer: wave w owns m-range [w*64, w*64+64) for all j ----
  {
    uint4 kf0[8], kf1[8];
    float nbk[8];
    #pragma unroll
    for (int jt = 0; jt < 8; ++jt){
      size_t jrow = grow0 + jt * 16 + l15;
      kf0[jt] = kh4[jrow * 8 + g];
      kf1[jt] = kh4[jrow * 8 + 4 + g];
      nbk[jt] = -fmaf(fmaf(DIAGC, rsk[jrow], km), L2E, 4.0f);
    }
    #pragma unroll
    for (int mt = 0; mt < 4; ++mt){
      int mrow = w * 64 + mt * 16 + l15;
      uint4 a0 = pj4[(size_t)mrow * 8 + g];
      uint4 a1 = pj4[(size_t)mrow * 8 + 4 + g];
      #pragma unroll
      for (int jt = 0; jt < 8; ++jt){
        int jr = jt * 16 + l15;
        f32x4 acc = {0.f, 0.f, 0.f, 0.f};
        acc = __builtin_amdgcn_mfma_f32_16x16x32_bf16(asb(a0), asb(kf0[jt]), acc, 0, 0, 0);
        acc = __builtin_amdgcn_mfma_f32_16x16x32_bf16(asb(a1), asb(kf1[jt]), acc, 0, 0, 0);
        uint2 u;
        u.x = bfpair(pexp(acc[0], nbk[jt]), pexp(acc[1], nbk[jt]));
        u.y = bfpair(pexp(acc[2], nbk[jt]), pexp(acc[3], nbk[jt]));
        int byte = jr * 512 + ((w * 128 + mt * 32 + g * 8) ^ ((jr & 7) << 4));
        *reinterpret_cast<uint2*>(lds + byte) = u;
      }
    }
  }

  // ---- B: phi(q) for both i-tiles, merged mt loop ----
  int its[2] = { w, 7 - w };
  int swb = 65536 + w * 4096 + l15 * 256;
  uint4 qf[2][8];
  f32x4 acc[2][5];
  {
    size_t irow0 = grow0 + its[0] * 16 + l15;
    size_t irow1 = grow0 + its[1] * 16 + l15;
    uint4 qb0_0 = qh4[irow0 * 8 + g];
    uint4 qb1_0 = qh4[irow0 * 8 + 4 + g];
    uint4 qb0_1 = qh4[irow1 * 8 + g];
    uint4 qb1_1 = qh4[irow1 * 8 + 4 + g];
    f32x4 aq0[16], aq1[16];
    #pragma unroll
    for (int mt = 0; mt < 16; ++mt){
      uint4 a0 = pj4[(size_t)(mt * 16 + l15) * 8 + g];
      uint4 a1 = pj4[(size_t)(mt * 16 + l15) * 8 + 4 + g];
      f32x4 x0 = {0.f, 0.f, 0.f, 0.f};
      x0 = __builtin_amdgcn_mfma_f32_16x16x32_bf16(asb(a0), asb(qb0_0), x0, 0, 0, 0);
      aq0[mt] = __builtin_amdgcn_mfma_f32_16x16x32_bf16(asb(a1), asb(qb1_0), x0, 0, 0, 0);
      f32x4 x1 = {0.f, 0.f, 0.f, 0.f};
      x1 = __builtin_amdgcn_mfma_f32_16x16x32_bf16(asb(a0), asb(qb0_1), x1, 0, 0, 0);
      aq1[mt] = __builtin_amdgcn_mfma_f32_16x16x32_bf16(asb(a1), asb(qb1_1), x1, 0, 0, 0);
    }
    // t=0
    {
      float mx = -3.0e38f;
      #pragma unroll
      for (int mt = 0; mt < 16; ++mt)
        mx = fmaxf(mx, fmaxf(fmaxf(aq0[mt][0], aq0[mt][1]), fmaxf(aq0[mt][2], aq0[mt][3])));
      mx = fmaxf(mx, __shfl_xor(mx, 16, 64));
      mx = fmaxf(mx, __shfl_xor(mx, 32, 64));
      float nb = -fmaf(fmaf(DIAGC, rsq[irow0], mx), L2E, 4.0f);
      #pragma unroll
      for (int half = 0; half < 2; ++half){
        #pragma unroll
        for (int mt = 0; mt < 8; ++mt){
          f32x4 a = aq0[half * 8 + mt];
          uint2 u;
          u.x = bfpair(pexp(a[0], nb), pexp(a[1], nb));
          u.y = bfpair(pexp(a[2], nb), pexp(a[3], nb));
          int byte = swb + ((mt * 32 + g * 8) ^ swz);
          *reinterpret_cast<uint2*>(lds + byte) = u;
        }
        #pragma unroll
        for (int ks = 0; ks < 4; ++ks){
          int byte = swb + ((ks * 64 + g * 16) ^ swz);
          qf[0][half * 4 + ks] = *reinterpret_cast<const uint4*>(lds + byte);
        }
      }
    }
    // t=1
    {
      float mx = -3.0e38f;
      #pragma unroll
      for (int mt = 0; mt < 16; ++mt)
        mx = fmaxf(mx, fmaxf(fmaxf(aq1[mt][0], aq1[mt][1]), fmaxf(aq1[mt][2], aq1[mt][3])));
      mx = fmaxf(mx, __shfl_xor(mx, 16, 64));
      mx = fmaxf(mx, __shfl_xor(mx, 32, 64));
      float nb = -fmaf(fmaf(DIAGC, rsq[irow1], mx), L2E, 4.0f);
      #pragma unroll
      for (int half = 0; half < 2; ++half){
        #pragma unroll
        for (int mt = 0; mt < 8; ++mt){
          f32x4 a = aq1[half * 8 + mt];
          uint2 u;
          u.x = bfpair(pexp(a[0], nb), pexp(a[1], nb));
          u.y = bfpair(pexp(a[2], nb), pexp(a[3], nb));
          int byte = swb + ((mt * 32 + g * 8) ^ swz);
          *reinterpret_cast<uint2*>(lds + byte) = u;
        }
        #pragma unroll
        for (int ks = 0; ks < 4; ++ks){
          int byte = swb + ((ks * 64 + g * 16) ^ swz);
          qf[1][half * 4 + ks] = *reinterpret_cast<const uint4*>(lds + byte);
        }
      }
    }
  }

  // ---- B2: shared-Sp prefix pass ----
  #pragma unroll
  for (int t = 0; t < 2; ++t)
    #pragma unroll
    for (int a5 = 0; a5 < 5; ++a5) acc[t][a5] = (f32x4){0.f, 0.f, 0.f, 0.f};
  #pragma unroll
  for (int ks = 0; ks < 8; ++ks){
    bf16x8 q0 = asb(qf[0][ks]);
    bf16x8 q1 = asb(qf[1][ks]);
    #pragma unroll
    for (int dt = 0; dt < 4; ++dt){
      uint4 spf = Spu[((size_t)blk * DD + dt * 16 + l15) * 32 + ks * 4 + g];
      acc[0][dt] = __builtin_amdgcn_mfma_f32_16x16x32_bf16(asb(spf), q0, acc[0][dt], 0, 0, 0);
      acc[1][dt] = __builtin_amdgcn_mfma_f32_16x16x32_bf16(asb(spf), q1, acc[1][dt], 0, 0, 0);
    }
    uint4 zfr = (l15 == 0) ? zbu[blk * 32 + ks * 4 + g] : zero4;
    acc[0][4] = __builtin_amdgcn_mfma_f32_16x16x32_bf16(asb(zfr), q0, acc[0][4], 0, 0, 0);
    acc[1][4] = __builtin_amdgcn_mfma_f32_16x16x32_bf16(asb(zfr), q1, acc[1][4], 0, 0, 0);
  }
  __syncthreads();

  // ---- C: scores (split accumulators) + PV + out, both i-tiles ----
  #pragma unroll
  for (int t = 0; t < 2; ++t){
    int it = its[t];
    int i = it * 16 + l15;
    int jtmax = it | 1;
    #pragma unroll
    for (int jt = 0; jt < 8; ++jt){
      if (jt <= jtmax){   // wave-uniform
        f32x4 sa0 = {0.f, 0.f, 0.f, 0.f};
        f32x4 sa1 = {0.f, 0.f, 0.f, 0.f};
        int jr = jt * 16 + l15;
        #pragma unroll
        for (int ks = 0; ks < 4; ++ks){
          int byte0 = jr * 512 + (((2 * ks) * 64 + g * 16) ^ ((jr & 7) << 4));
          int byte1 = jr * 512 + (((2 * ks + 1) * 64 + g * 16) ^ ((jr & 7) << 4));
          uint4 kfu0 = *reinterpret_cast<const uint4*>(lds + byte0);
          uint4 kfu1 = *reinterpret_cast<const uint4*>(lds + byte1);
          sa0 = __builtin_amdgcn_mfma_f32_16x16x32_bf16(asb(kfu0), asb(qf[t][2 * ks]), sa0, 0, 0, 0);
          sa1 = __builtin_amdgcn_mfma_f32_16x16x32_bf16(asb(kfu1), asb(qf[t][2 * ks + 1]), sa1, 0, 0, 0);
        }
        f32x4 sa = sa0 + sa1;
        int jb = jt * 16 + g * 4;
        uint2 u;
        u.x = bfpair((jb + 0 <= i) ? sa[0] : 0.f, (jb + 1 <= i) ? sa[1] : 0.f);
        u.y = bfpair((jb + 2 <= i) ? sa[2] : 0.f, (jb + 3 <= i) ? sa[3] : 0.f);
        int byte = swb + ((jt * 32 + g * 8) ^ swz);
        *reinterpret_cast<uint2*>(lds + byte) = u;
      }
    }
    int ksmax = it >> 1;
    #pragma unroll
    for (int ks = 0; ks < 4; ++ks){
      if (ks <= ksmax){   // wave-uniform
        int byte = swb + ((ks * 64 + g * 16) ^ swz);
        uint4 sfu = *reinterpret_cast<const uint4*>(lds + byte);
        bf16x8 sf = asb(sfu);
        #pragma unroll
        for (int dt = 0; dt < 4; ++dt){
          uint4 vfu = vTu[((size_t)(bh * DD + dt * 16 + l15)) * 512 + c * 16 + ks * 4 + g];
          acc[t][dt] = __builtin_amdgcn_mfma_f32_16x16x32_bf16(asb(vfu), sf, acc[t][dt], 0, 0, 0);
        }
        uint4 of = (l15 == 0) ? ones4 : zero4;
        acc[t][4] = __builtin_amdgcn_mfma_f32_16x16x32_bf16(asb(of), sf, acc[t][4], 0, 0, 0);
      }
    }
    float den = __shfl(acc[t][4][0], l15, 64);
    float inv = 1.f / den;
    size_t obase = ((size_t)(b * LL + c * CC + i)) * EE + h * DD;
    #pragma unroll
    for (int dt = 0; dt < 4; ++dt){
      ushort4 pk;
      pk.x = f2bf(acc[t][dt][0] * inv); pk.y = f2bf(acc[t][dt][1] * inv);
      pk.z = f2bf(acc[t][dt][2] * inv); pk.w = f2bf(acc[t][dt][3] * inv);
      *reinterpret_cast<ushort4*>(attnb + obase + dt * 16 + g * 4) = pk;
    }
  }
}

// ---------------- K6: MFMA out-proj v2 — LDS-staged Woutb panel + pipelined ks ----------
__global__ __launch_bounds__(256, 2) void k_proj_M2(const unsigned short* __restrict__ attnb,
                                                    const unsigned short* __restrict__ Woutb,
                                                    const float* __restrict__ bout,
                                                    float* __restrict__ out){
  __shared__ unsigned short Wl[64 * 512];   // 64KB: 8 ktiles of 64x64, swizzled
  int tid = threadIdx.x;
  int w = tid >> 6, lane = tid & 63, l15 = lane & 15, g = lane >> 4;
  int rb = blockIdx.x & 63, eb = blockIdx.x >> 6;   // eb-siblings share an XCD (64%8==0)
  int r0 = rb * 256, e0 = eb * 64;
  const uint4* at4 = reinterpret_cast<const uint4*>(attnb);
  const uint4* Wo4 = reinterpret_cast<const uint4*>(Woutb);
  for (int idx = tid; idx < 4096; idx += 256){
    int row = idx >> 6, rest = idx & 63, kt = rest >> 3, ch = rest & 7;
    uint4 v = Wo4[(size_t)(e0 + row) * 64 + kt * 8 + ch];
    int byte = kt * 8192 + row * 128 + ((ch * 16) ^ ((row & 7) << 4));
    *reinterpret_cast<uint4*>(reinterpret_cast<char*>(Wl) + byte) = v;
  }
  __syncthreads();
  const char* Wc = reinterpret_cast<const char*>(Wl);
  f32x4 acc[4][4];   // [rt][ct]
  #pragma unroll
  for (int rt = 0; rt < 4; ++rt)
    #pragma unroll
    for (int ct = 0; ct < 4; ++ct) acc[rt][ct] = (f32x4){0.f, 0.f, 0.f, 0.f};
  size_t rbase = (size_t)(r0 + w * 64 + l15) * 64;   // uint4 units (EE*2B/16)
  #pragma unroll 4
  for (int ks = 0; ks < 16; ++ks){
    uint4 bfr[4];
    #pragma unroll
    for (int rt = 0; rt < 4; ++rt)
      bfr[rt] = at4[rbase + (size_t)rt * 16 * 64 + ks * 4 + g];
    int kt = ks >> 1, k2 = ks & 1;
    #pragma unroll
    for (int ct = 0; ct < 4; ++ct){
      int row = ct * 16 + l15;
      int byte = kt * 8192 + row * 128 + ((k2 * 64 + g * 16) ^ ((row & 7) << 4));
      uint4 af = *reinterpret_cast<const uint4*>(Wc + byte);
      bf16x8 afb = asb(af);
      #pragma unroll
      for (int rt = 0; rt < 4; ++rt)
        acc[rt][ct] = __builtin_amdgcn_mfma_f32_16x16x32_bf16(afb, asb(bfr[rt]), acc[rt][ct], 0, 0, 0);
    }
  }
  #pragma unroll
  for (int ct = 0; ct < 4; ++ct){
    int e = e0 + ct * 16 + g * 4;
    float4 bo = *reinterpret_cast<const float4*>(bout + e);
    #pragma unroll
    for (int rt = 0; rt < 4; ++rt){
      int r = r0 + w * 64 + rt * 16 + l15;
      float4 o;
      o.x = acc[rt][ct][0] + bo.x; o.y = acc[rt][ct][1] + bo.y;
      o.z = acc[rt][ct][2] + bo.z; o.w = acc[rt][ct][3] + bo.w;
      *reinterpret_cast<float4*>(out + (size_t)r * EE + e) = o;
    }
  }
}

extern "C" void kernel_launch(void* const* d_in, const int* in_sizes, int n_in,
                              void* d_out, int out_size, void* d_ws, size_t ws_size,
                              hipStream_t stream){
  const float* queries = (const float*)d_in[0];
  const float* keys    = (const float*)d_in[1];
  const float* values  = (const float*)d_in[2];
  const float* Wq      = (const float*)d_in[3];
  const float* Wk      = (const float*)d_in[4];
  const float* Wv      = (const float*)d_in[5];
  const float* Wout    = (const float*)d_in[6];
  const float* bout    = (const float*)d_in[7];
  const float* proj    = (const float*)d_in[8];

  // workspace layout (~104 MB, no aliasing)
  char* ws = (char*)d_ws;
  unsigned short* qhb  = (unsigned short*)(ws + 0);           // 16.8M [BH,L,D]
  unsigned short* khb  = (unsigned short*)(ws + 16777216);    // 16.8M
  unsigned short* vTb  = (unsigned short*)(ws + 33554432);    // 16.8M [BH,D,L]
  unsigned short* SpT  = (unsigned short*)(ws + 50331648);    // 33.5M [BH,NCH,D,M]
  unsigned short* attnb= (unsigned short*)(ws + 83886080);    // 16.8M [B,L,E]
  float*          zfbuf= (float*)(ws + 100663296);            // 1.0M
  unsigned short* zb   = (unsigned short*)(ws + 101711872);   // 0.5M
  float*          rsq  = (float*)(ws + 102236160);            // 0.5M
  float*          rsk  = (float*)(ws + 102760448);            // 0.5M
  unsigned short* Woutb= (unsigned short*)(ws + 103284736);   // 0.5M
  unsigned short* projb= (unsigned short*)(ws + 103809024);   // 32K  [M,D] bf16 (DN folded)
  unsigned*       kmax = (unsigned*)(ws + 103841792);         // 4
  float*          out  = (float*)d_out;

  hipMemsetAsync(kmax, 0, 4, stream);

  k_cvt<<<dim3(544), dim3(256), 0, stream>>>(Wout, Woutb, proj, projb);

  k_qkv<<<dim3(BHN * 32), dim3(256), 0, stream>>>(queries, keys, values, Wq, Wk, Wv,
                                                  qhb, khb, vTb, rsq, rsk);

  k_kmaxM<<<dim3(256), dim3(256), 0, stream>>>(khb, projb, kmax);

  k_chunkKV6<<<dim3(BHN * NCH), dim3(256), 0, stream>>>(khb, projb, rsk, kmax, vTb, SpT, zfbuf);

  k_prefix<<<dim3(516), dim3(256), 0, stream>>>(SpT, zfbuf, zb);

  k_cattn10<<<dim3(BHN * NCH), dim3(256), 0, stream>>>(qhb, khb, projb, rsq, rsk, kmax,
                                                       vTb, SpT, zb, attnb);

  k_proj_M2<<<dim3(512), dim3(256), 0, stream>>>(attnb, Woutb, bout, out);
}